// Round 7
// baseline (154.259 us; speedup 1.0000x reference)
//
#include <hip/hip_runtime.h>

// SpDepthWSepaConv3d: out[i,c] = bias[c] + sum_k mask[k,i] * features[pair_in[k,i],c] * weight[k,c]
// Pure gather (pair_out[k][i]==i when mask set). All int inputs are int32 on device.
//
// R7: R6 was latency-bound on the per-tap serial chain (replays with L3-resident
// inputs ran at identical 47.6us -> not BW-bound). Changes:
//  - Speculative center tap: reference construction guarantees mask[13]=1,
//    pair_in[13][i]=i; we load features[vox] up-front (independent of meta)
//    and VERIFY (bit13 && pin13==vox) before using, so correctness never
//    depends on the assumption. ~70% of voxels then skip the gather loop.
//  - Gather loop batched by 2: both loads issued before either is consumed.
//  - 8 voxels/wave: 16 meta + 8 center loads in flight up front.
//  - Nontemporal out stores (write-only) to preserve L2 for gathers.
// Block = 4 waves x 8 voxels = 32 consecutive voxels (meta lines fully used).

#define KVOL 27
#define VPW  8    // voxels per wave
#define WPB  4    // waves per block -> 32 consecutive voxels per block

__global__ __launch_bounds__(256) void spconv_dw_kernel(
    const float* __restrict__ features,   // [n, 64]
    const float* __restrict__ weight,     // [27, 64]
    const float* __restrict__ bias,       // [64]
    const int* __restrict__ pair_in,      // [27, n] int32
    const int* __restrict__ pair_mask,    // [27, n] int32 (0/1)
    float* __restrict__ out,              // [n, 64]
    int n)
{
    const int t     = threadIdx.x;
    const int w     = t >> 6;                        // wave in block
    const int c     = t & 63;                        // channel / tap lane
    const int vbase = blockIdx.x * (VPW * WPB) + w * VPW;

    // Up-front independent loads: meta (lane-parallel, lane c = tap c) and
    // speculative center-tap features row for each voxel. All in flight at once.
    int   m[VPW], p[VPW];
    float fc[VPW];
    #pragma unroll
    for (int s = 0; s < VPW; ++s) { m[s] = 0; p[s] = 0; fc[s] = 0.0f; }

    #pragma unroll
    for (int s = 0; s < VPW; ++s) {
        const int vox = vbase + s;
        if (vox < n) {
            if (c < KVOL) {
                const size_t off = (size_t)c * n + vox;
                m[s] = pair_mask[off];
                p[s] = pair_in[off];
            }
            fc[s] = features[(size_t)vox * 64 + c];   // speculative center gather
        }
    }

    const float b   = bias[c];
    const float w13 = weight[13 * 64 + c];

    #pragma unroll
    for (int s = 0; s < VPW; ++s) {
        const int vox = vbase + s;                   // wave-uniform
        if (vox >= n) break;

        unsigned long long found = __ballot(m[s] != 0);
        float acc = b;

        // Verified speculative center tap (condition wave-uniform).
        const int pin13 = __shfl(p[s], 13);
        if (((found >> 13) & 1ull) && pin13 == vox) {
            acc = fmaf(fc[s], w13, acc);
            found &= ~(1ull << 13);
        }

        // Residual taps (~0.35/voxel): batch 2 loads in flight per iteration.
        while (found) {
            const int k0 = __ffsll(found) - 1; found &= found - 1;
            const bool has1 = (found != 0);
            int k1 = k0;
            if (has1) { k1 = __ffsll(found) - 1; found &= found - 1; }
            const int pin0 = __shfl(p[s], k0);
            const int pin1 = __shfl(p[s], k1);
            const float f0 = features[(size_t)pin0 * 64 + c];
            const float f1 = features[(size_t)pin1 * 64 + c];
            acc = fmaf(f0, weight[k0 * 64 + c], acc);
            if (has1) acc = fmaf(f1, weight[k1 * 64 + c], acc);
        }

        __builtin_nontemporal_store(acc, &out[(size_t)vox * 64 + c]);
    }
}

extern "C" void kernel_launch(void* const* d_in, const int* in_sizes, int n_in,
                              void* d_out, int out_size, void* d_ws, size_t ws_size,
                              hipStream_t stream) {
    const float* features  = (const float*)d_in[0];
    const float* weight    = (const float*)d_in[1];
    const float* bias      = (const float*)d_in[2];
    const int* pair_in     = (const int*)d_in[3];
    // d_in[4] = pair_out — unused (pure gather)
    const int* pair_mask   = (const int*)d_in[5];
    float* out             = (float*)d_out;

    const int n = in_sizes[0] / 64;                       // N = 150000
    const int vpb = VPW * WPB;                            // 32 voxels per block
    const int blocks = (n + vpb - 1) / vpb;

    spconv_dw_kernel<<<blocks, 256, 0, stream>>>(
        features, weight, bias, pair_in, pair_mask, out, n);
}

// Round 8
// 136.600 us; speedup vs baseline: 1.1293x; 1.1293x over previous
//
#include <hip/hip_runtime.h>

// SpDepthWSepaConv3d: out[i,c] = bias[c] + sum_k mask[k,i] * features[pair_in[k,i],c] * weight[k,c]
// Pure gather (pair_out[k][i]==i when mask set). All int inputs are int32 on device.
//
// R8: R6/R7 were vector-memory-PIPE bound, not BW bound (replays with
// L3-resident inputs ran at identical time). The killer was the lane-parallel
// pair_in scatter (27 distinct lines per load instr) + per-tap __shfl chains.
// Changes vs R6:
//  - pair_in is never scatter-loaded. Inside the tap loop all 64 lanes load
//    the SAME address pair_in[k*n+vox] -> broadcast, 1 line, and no __shfl.
//  - Center tap (k=13; construction guarantees mask=1, pin=vox) speculated:
//    features[vox] + pair_in[13*n+vox] loaded up front (independent), used
//    only after verification -> ~70% of voxels skip the gather loop.
//  - Mask scatter (lanes 0..26) kept — needed for the ballot tap set.
//  - VPW=4, 16 consecutive voxels per block (meta lines fully used in L1).

#define KVOL 27
#define VPW  4    // voxels per wave
#define WPB  4    // waves per block -> 16 consecutive voxels per block

__global__ __launch_bounds__(256) void spconv_dw_kernel(
    const float* __restrict__ features,   // [n, 64]
    const float* __restrict__ weight,     // [27, 64]
    const float* __restrict__ bias,       // [64]
    const int* __restrict__ pair_in,      // [27, n] int32
    const int* __restrict__ pair_mask,    // [27, n] int32 (0/1)
    float* __restrict__ out,              // [n, 64]
    int n)
{
    const int t     = threadIdx.x;
    const int w     = t >> 6;                        // wave in block
    const int c     = t & 63;                        // channel / tap lane
    const int vbase = blockIdx.x * (VPW * WPB) + w * VPW;

    // Up-front independent loads (all in flight together):
    //  - mask scatter (lanes 0..26), 27 lines
    //  - center pin broadcast (1 line) and center feature row (4 lines) per voxel
    int   m[VPW], pin13[VPW];
    float fc[VPW];
    #pragma unroll
    for (int s = 0; s < VPW; ++s) { m[s] = 0; pin13[s] = -1; fc[s] = 0.0f; }

    #pragma unroll
    for (int s = 0; s < VPW; ++s) {
        const int vox = vbase + s;
        if (vox < n) {
            if (c < KVOL) m[s] = pair_mask[(size_t)c * n + vox];
            pin13[s] = pair_in[(size_t)13 * n + vox];       // broadcast (uniform addr)
            fc[s]    = features[(size_t)vox * 64 + c];      // speculative center row
        }
    }

    const float b   = bias[c];
    const float w13 = weight[13 * 64 + c];

    #pragma unroll
    for (int s = 0; s < VPW; ++s) {
        const int vox = vbase + s;                   // wave-uniform
        if (vox >= n) break;

        unsigned long long found = __ballot(m[s] != 0);
        float acc = b;

        // Verified speculative center tap (condition wave-uniform).
        if (((found >> 13) & 1ull) && pin13[s] == vox) {
            acc = fmaf(fc[s], w13, acc);
            found &= ~(1ull << 13);
        }

        // Residual taps (~0.35/voxel). pin load is a wave-uniform broadcast
        // (1 line, no shfl); gather is 256B coalesced.
        while (found) {
            const int k = __ffsll(found) - 1;
            found &= found - 1;
            const int pin = pair_in[(size_t)k * n + vox];
            acc = fmaf(features[(size_t)pin * 64 + c], weight[k * 64 + c], acc);
        }

        __builtin_nontemporal_store(acc, &out[(size_t)vox * 64 + c]);
    }
}

extern "C" void kernel_launch(void* const* d_in, const int* in_sizes, int n_in,
                              void* d_out, int out_size, void* d_ws, size_t ws_size,
                              hipStream_t stream) {
    const float* features  = (const float*)d_in[0];
    const float* weight    = (const float*)d_in[1];
    const float* bias      = (const float*)d_in[2];
    const int* pair_in     = (const int*)d_in[3];
    // d_in[4] = pair_out — unused (pure gather)
    const int* pair_mask   = (const int*)d_in[5];
    float* out             = (float*)d_out;

    const int n = in_sizes[0] / 64;                       // N = 150000
    const int vpb = VPW * WPB;                            // 16 voxels per block
    const int blocks = (n + vpb - 1) / vpb;

    spconv_dw_kernel<<<blocks, 256, 0, stream>>>(
        features, weight, bias, pair_in, pair_mask, out, n);
}

// Round 9
// 133.713 us; speedup vs baseline: 1.1537x; 1.0216x over previous
//
#include <hip/hip_runtime.h>

// SpDepthWSepaConv3d: out[i,c] = bias[c] + sum_k mask[k,i] * features[pair_in[k,i],c] * weight[k,c]
// Pure gather (pair_out[k][i]==i when mask set). All int inputs are int32 on device.
//
// R9: R8's last scattered access was the mask scatter (lane c -> pair_mask
// [c*n+vox], 27 lines per load instr -> ~27 TA cycles each, head of every
// voxel's dependent chain). Split into two kernels:
//  K1 (meta compact, lane=voxel, fully coalesced): bits[vox] = found-set;
//     center tap (k=13) verified (mask && pin==vox) -> bit31, bit13 cleared.
//     Writes one u32/voxel into d_ws.
//  K2 (= R8 envelope): meta is ONE broadcast word/voxel (1 line, L1-shared
//     by 16 voxels); no ballot, no scatter; residual taps (~0.35/voxel) load
//     pin via wave-uniform broadcast; scalar loop via readfirstlane.

#define KVOL 27
#define VPW  4    // voxels per wave (K2)
#define WPB  4    // waves per block -> 16 consecutive voxels per block (K2)

__global__ __launch_bounds__(256) void spconv_meta_kernel(
    const int* __restrict__ pair_in,      // [27, n]
    const int* __restrict__ pair_mask,    // [27, n]
    unsigned int* __restrict__ bits_ws,   // [n]
    int n)
{
    const int vox = blockIdx.x * 256 + threadIdx.x;
    if (vox >= n) return;

    unsigned int bits = 0;
    #pragma unroll
    for (int k = 0; k < KVOL; ++k) {                    // 27 coalesced loads
        const int mv = pair_mask[(size_t)k * n + vox];
        bits |= (mv != 0 ? 1u : 0u) << k;
    }
    const int pin13 = pair_in[(size_t)13 * n + vox];    // coalesced
    if ((bits & (1u << 13)) && pin13 == vox)
        bits = (bits & ~(1u << 13)) | 0x80000000u;      // center verified

    bits_ws[vox] = bits;
}

__global__ __launch_bounds__(256) void spconv_dw_kernel(
    const float* __restrict__ features,   // [n, 64]
    const float* __restrict__ weight,     // [27, 64]
    const float* __restrict__ bias,       // [64]
    const int* __restrict__ pair_in,      // [27, n]
    const unsigned int* __restrict__ bits_ws, // [n] compacted meta
    float* __restrict__ out,              // [n, 64]
    int n)
{
    const int t     = threadIdx.x;
    const int w     = t >> 6;                        // wave in block
    const int c     = t & 63;                        // channel
    const int vbase = blockIdx.x * (VPW * WPB) + w * VPW;

    // Up-front independent loads: meta broadcast word + center feature row.
    unsigned int bitsv[VPW];
    float fc[VPW];
    #pragma unroll
    for (int s = 0; s < VPW; ++s) { bitsv[s] = 0; fc[s] = 0.0f; }

    #pragma unroll
    for (int s = 0; s < VPW; ++s) {
        const int vox = vbase + s;
        if (vox < n) {
            bitsv[s] = bits_ws[vox];                    // broadcast, 1 line/16 vox
            fc[s]    = features[(size_t)vox * 64 + c];  // coalesced 256B row
        }
    }

    const float b   = bias[c];
    const float w13 = weight[13 * 64 + c];

    #pragma unroll
    for (int s = 0; s < VPW; ++s) {
        const int vox = vbase + s;                   // wave-uniform
        if (vox >= n) break;

        const unsigned int bv = __builtin_amdgcn_readfirstlane(bitsv[s]);
        float acc = b;

        if (bv & 0x80000000u)                        // verified center tap
            acc = fmaf(fc[s], w13, acc);

        unsigned int found = bv & 0x07FFFFFFu;       // residual taps (~0.35/vox)
        while (found) {
            const int k = __builtin_ctz(found);
            found &= found - 1;
            const int pin = pair_in[(size_t)k * n + vox];   // broadcast, 1 line
            acc = fmaf(features[(size_t)pin * 64 + c], weight[k * 64 + c], acc);
        }

        __builtin_nontemporal_store(acc, &out[(size_t)vox * 64 + c]);
    }
}

extern "C" void kernel_launch(void* const* d_in, const int* in_sizes, int n_in,
                              void* d_out, int out_size, void* d_ws, size_t ws_size,
                              hipStream_t stream) {
    const float* features  = (const float*)d_in[0];
    const float* weight    = (const float*)d_in[1];
    const float* bias      = (const float*)d_in[2];
    const int* pair_in     = (const int*)d_in[3];
    // d_in[4] = pair_out — unused (pure gather)
    const int* pair_mask   = (const int*)d_in[5];
    float* out             = (float*)d_out;
    unsigned int* bits_ws  = (unsigned int*)d_ws;

    const int n = in_sizes[0] / 64;                       // N = 150000

    const int blocks1 = (n + 255) / 256;
    spconv_meta_kernel<<<blocks1, 256, 0, stream>>>(pair_in, pair_mask, bits_ws, n);

    const int vpb = VPW * WPB;                            // 16 voxels per block
    const int blocks2 = (n + vpb - 1) / vpb;
    spconv_dw_kernel<<<blocks2, 256, 0, stream>>>(
        features, weight, bias, pair_in, bits_ws, out, n);
}

// Round 11
// 132.280 us; speedup vs baseline: 1.1662x; 1.0108x over previous
//
#include <hip/hip_runtime.h>

// SpDepthWSepaConv3d: out[i,c] = bias[c] + sum_k mask[k,i] * features[pair_in[k,i],c] * weight[k,c]
// Pure gather (pair_out[k][i]==i when mask set). All int inputs are int32 on device.
//
// R11 = R10 with the compile fix: __builtin_nontemporal_store requires a
// native vector type, not HIP's float4 class -> use ext_vector_type(4).
//
// R10 theory: K2's bulk path was vmem-instruction bound (~3 scalar-float vmem
// ops per voxel, each with exposed vmcnt latency). Lane layout: sub=lane>>4
// picks one of 4 voxels, c4=lane&15 picks a float4 of channels -> ONE
// instruction loads/stores 4 voxel rows (1KB/wave). Residual taps (~0.35/vox)
// loop over the wave-union of 4 voxels' tap bits, per-lane masked by multiply
// (pin=0 is a valid row when tap absent -> gather always safe, L1-hot).
// K1 (meta compact): bits[vox] = tap set; center tap verified
// (mask13 && pin13==vox) -> bit31, bit13 cleared.

#define KVOL 27

typedef float vf4 __attribute__((ext_vector_type(4)));

__global__ __launch_bounds__(256) void spconv_meta_kernel(
    const int* __restrict__ pair_in,      // [27, n]
    const int* __restrict__ pair_mask,    // [27, n]
    unsigned int* __restrict__ bits_ws,   // [n]
    int n)
{
    const int vox = blockIdx.x * 256 + threadIdx.x;
    if (vox >= n) return;

    unsigned int bits = 0;
    #pragma unroll
    for (int k = 0; k < KVOL; ++k) {                    // 27 coalesced loads
        const int mv = pair_mask[(size_t)k * n + vox];
        bits |= (mv != 0 ? 1u : 0u) << k;
    }
    const int pin13 = pair_in[(size_t)13 * n + vox];    // coalesced
    if ((bits & (1u << 13)) && pin13 == vox)
        bits = (bits & ~(1u << 13)) | 0x80000000u;      // center verified

    bits_ws[vox] = bits;
}

// wave = 8 voxels (2 quad-groups), block = 4 waves = 32 consecutive voxels
#define GPW  2    // quad-groups per wave
#define VPB  32   // voxels per block

__global__ __launch_bounds__(256) void spconv_dw_kernel(
    const float* __restrict__ features,   // [n, 64]
    const float* __restrict__ weight,     // [27, 64]
    const float* __restrict__ bias,       // [64]
    const int* __restrict__ pair_in,      // [27, n]
    const unsigned int* __restrict__ bits_ws, // [n] compacted meta
    float* __restrict__ out,              // [n, 64]
    int n)
{
    const int t     = threadIdx.x;
    const int w     = t >> 6;                  // wave in block
    const int lane  = t & 63;
    const int sub   = lane >> 4;               // voxel within quad
    const int c4    = lane & 15;               // float4 index within 64 channels
    const int wbase = blockIdx.x * VPB + w * (GPW * 4);

    // Up-front independent loads for both quad-groups.
    int voxl[GPW], voxc[GPW];
    unsigned int bitsv[GPW];
    vf4 fc[GPW];
    #pragma unroll
    for (int g = 0; g < GPW; ++g) {
        voxl[g] = wbase + g * 4 + sub;
        voxc[g] = voxl[g] < n ? voxl[g] : (n - 1);           // clamp for loads
        bitsv[g] = bits_ws[voxc[g]];                          // quad-uniform word
        fc[g] = ((const vf4*)&features[(size_t)voxc[g] * 64])[c4];  // 1KB/wave
    }

    const vf4 bv  = ((const vf4*)bias)[c4];
    const vf4 w13 = ((const vf4*)&weight[13 * 64])[c4];

    #pragma unroll
    for (int g = 0; g < GPW; ++g) {
        const unsigned int bits = bitsv[g];

        // center tap: per-lane mask-by-multiply (≈always set, verified in K1)
        const float m13 = (bits & 0x80000000u) ? 1.0f : 0.0f;
        vf4 acc = bv + (fc[g] * m13) * w13;   // element-wise on native vectors

        // residual taps: loop over wave-union of the 4 voxels' tap sets
        unsigned int res = bits & 0x07FFFFFFu;
        unsigned int uni = res | __shfl_xor(res, 16);
        uni |= __shfl_xor(uni, 32);
        uni = __builtin_amdgcn_readfirstlane(uni);

        while (uni) {
            const int k = __builtin_ctz(uni);
            uni &= uni - 1;
            const float sel = (res >> k) & 1u ? 1.0f : 0.0f;
            const int pin = pair_in[(size_t)k * n + voxc[g]]; // quad-uniform addr
            const vf4 f  = ((const vf4*)&features[(size_t)pin * 64])[c4];
            const vf4 wk = ((const vf4*)&weight[k * 64])[c4];
            acc += (f * sel) * wk;
        }

        if (voxl[g] < n)
            __builtin_nontemporal_store(acc,
                (vf4*)&out[(size_t)voxl[g] * 64 + c4 * 4]);
    }
}

extern "C" void kernel_launch(void* const* d_in, const int* in_sizes, int n_in,
                              void* d_out, int out_size, void* d_ws, size_t ws_size,
                              hipStream_t stream) {
    const float* features  = (const float*)d_in[0];
    const float* weight    = (const float*)d_in[1];
    const float* bias      = (const float*)d_in[2];
    const int* pair_in     = (const int*)d_in[3];
    // d_in[4] = pair_out — unused (pure gather)
    const int* pair_mask   = (const int*)d_in[5];
    float* out             = (float*)d_out;
    unsigned int* bits_ws  = (unsigned int*)d_ws;

    const int n = in_sizes[0] / 64;                       // N = 150000

    const int blocks1 = (n + 255) / 256;
    spconv_meta_kernel<<<blocks1, 256, 0, stream>>>(pair_in, pair_mask, bits_ws, n);

    const int blocks2 = (n + VPB - 1) / VPB;
    spconv_dw_kernel<<<blocks2, 256, 0, stream>>>(
        features, weight, bias, pair_in, bits_ws, out, n);
}